// Round 9
// baseline (104.758 us; speedup 1.0000x reference)
//
#include <hip/hip_runtime.h>
#include <math.h>

// VQ quantizer: x [512,256,12] fp32, codebook [512,12] fp32.
// Outputs (concat fp32): quantized_st [512*256*12], indices-as-float [512*256], loss [1].
//
// R9 structure: CODEBOOK IN REGISTERS (8 codes/lane, one wave = all 512 codes),
// tokens broadcast one at a time. Kills the R4-R8 LDS-broadcast bottleneck
// (codebook ds_read stream at rho~1); hot loop uses no shared memory at all.
namespace {
constexpr int KCB   = 512;
constexpr int DIM   = 12;
constexpr int NTOK  = 512 * 256;       // 131072
constexpr int QSIZE = NTOK * DIM;      // 1572864
constexpr int CPL   = 8;               // codes per lane: 64 lanes x 8 = 512
constexpr int TPW   = 32;              // tokens per wave
constexpr int NWAVE = NTOK / TPW;      // 4096 waves = 1024 blocks x 4 waves
constexpr float LSCALE = 1.25f / (float)QSIZE;

// launch_bounds(256,3): VGPR cap 2048/12 = 170 — comfortably fits the ~145
// live regs (codes 104 + token 13 + chains ~20) WITHOUT tripping the 128-cap
// spill behavior seen in R5/R6 at 512-thr blocks. 12 waves/CU = 3/SIMD.
__global__ __launch_bounds__(256, 3) void vq_main(const float* __restrict__ x,
                                                  const float* __restrict__ cb,
                                                  float* __restrict__ out,
                                                  float* __restrict__ partials) {
    const int tid  = threadIdx.x;
    const int lane = tid & 63;
    const int wv   = __builtin_amdgcn_readfirstlane(tid >> 6);
    const int wgid = blockIdx.x * 4 + wv;     // 0..4095
    const int tb   = wgid * TPW;              // this wave's 32 tokens

    // ---- one-time: load this lane's 8 codes (idx = 64j+lane; for fixed j the
    // wave's loads are lane-contiguous 48B rows -> coalesced) + w2 via the
    // EXACT fmaf chain validated R1-R8 (bitwise == pack_cb's contracted form).
    float cw[CPL][DIM];
    float w2[CPL];
#pragma unroll
    for (int j = 0; j < CPL; ++j) {
        const float4* cr = (const float4*)(cb + (size_t)(j * 64 + lane) * DIM);
        float4 c0 = cr[0], c1 = cr[1], c2 = cr[2];
        cw[j][0] = c0.x; cw[j][1] = c0.y; cw[j][2]  = c0.z; cw[j][3]  = c0.w;
        cw[j][4] = c1.x; cw[j][5] = c1.y; cw[j][6]  = c1.z; cw[j][7]  = c1.w;
        cw[j][8] = c2.x; cw[j][9] = c2.y; cw[j][10] = c2.z; cw[j][11] = c2.w;
        float t2 = 0.f;
#pragma unroll
        for (int d = 0; d < DIM; ++d) t2 = fmaf(cw[j][d], cw[j][d], t2);
        w2[j] = t2;
    }

    float losssum = 0.f;
    float idxbuf  = 0.f;

    for (int t = 0; t < TPW; ++t) {
        // token broadcast: uniform address -> scalar (s_load) or L1-broadcast
        // vector load; either pipe is far below its ceiling at 3 loads/token.
        const float* xr = x + (size_t)(tb + t) * DIM;
        float4 a0 = *(const float4*)(xr + 0);
        float4 a1 = *(const float4*)(xr + 4);
        float4 a2 = *(const float4*)(xr + 8);
        float xv[DIM] = {a0.x, a0.y, a0.z, a0.w, a1.x, a1.y, a1.z, a1.w,
                         a2.x, a2.y, a2.z, a2.w};
        float x2 = 0.f;
#pragma unroll
        for (int d = 0; d < DIM; ++d) x2 = fmaf(xv[d], xv[d], x2);   // chain == R1-R8

        // 8 codes/lane, EXACT score sequence validated R1-R8. Within-lane idx
        // ascends with j (idx = 64j+lane) -> strict < keeps first occurrence.
        float best = INFINITY;
        int   bidx = 0;
        int   kk   = lane;
#pragma unroll
        for (int j = 0; j < CPL; ++j) {
            float xw = 0.f;
            xw = fmaf(xv[0],  cw[j][0],  xw);
            xw = fmaf(xv[1],  cw[j][1],  xw);
            xw = fmaf(xv[2],  cw[j][2],  xw);
            xw = fmaf(xv[3],  cw[j][3],  xw);
            xw = fmaf(xv[4],  cw[j][4],  xw);
            xw = fmaf(xv[5],  cw[j][5],  xw);
            xw = fmaf(xv[6],  cw[j][6],  xw);
            xw = fmaf(xv[7],  cw[j][7],  xw);
            xw = fmaf(xv[8],  cw[j][8],  xw);
            xw = fmaf(xv[9],  cw[j][9],  xw);
            xw = fmaf(xv[10], cw[j][10], xw);
            xw = fmaf(xv[11], cw[j][11], xw);
            float dsc = fmaf(-2.f, xw, x2) + w2[j];
            bool c = dsc < best;
            best = c ? dsc : best;
            bidx = c ? kk : bidx;
            kk += 64;
        }

        // cross-lane exact argmin: fmin butterfly (min is order-insensitive,
        // bitwise exact), then ballot picks the winner lane.
        float smin = best;
#pragma unroll
        for (int off = 1; off < 64; off <<= 1)
            smin = fminf(smin, __shfl_xor(smin, off));

        unsigned long long mask = __ballot(best == smin);
        int widx;
        if (mask & (mask - 1)) {
            // rare: >=2 lanes hold bitwise-equal minimal scores (incl. the
            // -0/+0 case) -> exact first-occurrence = min idx among them.
            int cand = (best == smin) ? bidx : 0x7fffffff;
#pragma unroll
            for (int off = 1; off < 64; off <<= 1) {
                int o = __shfl_xor(cand, off);
                cand = o < cand ? o : cand;
            }
            widx = cand;
        } else {
            widx = __builtin_amdgcn_readlane(bidx, (int)__builtin_ctzll(mask));
        }

        idxbuf  = (lane == t) ? (float)widx : idxbuf;   // lane t keeps token t's idx
        losssum = fmaf(smin, LSCALE, losssum);          // min dist == sum_d(q-x)^2
    }

    // ---- emit: lanes 0..31 finalize tokens tb+lane (coalesced 48B rows).
    if (lane < TPW) {
        const int t   = tb + lane;
        const int bid = (int)idxbuf;
        const float4* xp = (const float4*)(x + (size_t)t * DIM);
        float4 a0 = xp[0], a1 = xp[1], a2 = xp[2];
        const float4* wr = (const float4*)(cb + (size_t)bid * DIM);
        float4 q0 = wr[0], q1 = wr[1], q2 = wr[2];
        float4 r0, r1, r2;   // quantized_st = x + (q - x), mirrors reference rounding
        r0.x = a0.x + (q0.x - a0.x); r0.y = a0.y + (q0.y - a0.y);
        r0.z = a0.z + (q0.z - a0.z); r0.w = a0.w + (q0.w - a0.w);
        r1.x = a1.x + (q1.x - a1.x); r1.y = a1.y + (q1.y - a1.y);
        r1.z = a1.z + (q1.z - a1.z); r1.w = a1.w + (q1.w - a1.w);
        r2.x = a2.x + (q2.x - a2.x); r2.y = a2.y + (q2.y - a2.y);
        r2.z = a2.z + (q2.z - a2.z); r2.w = a2.w + (q2.w - a2.w);
        float4* qo = (float4*)(out + (size_t)t * DIM);
        qo[0] = r0; qo[1] = r1; qo[2] = r2;
        out[QSIZE + t] = (float)bid;
    }
    if (lane == 0) partials[wgid] = losssum;   // per-wave loss partial (no atomics)
}

// 4096 wave partials -> loss scalar. Single block; overwrites the slot, so no
// zero-init dispatch is needed.
__global__ __launch_bounds__(1024) void reduce_loss(const float* __restrict__ p,
                                                    float* __restrict__ out) {
    float v = (p[threadIdx.x] + p[threadIdx.x + 1024]) +
              (p[threadIdx.x + 2048] + p[threadIdx.x + 3072]);
#pragma unroll
    for (int off = 32; off > 0; off >>= 1) v += __shfl_down(v, off);
    __shared__ float r[16];
    if ((threadIdx.x & 63) == 0) r[threadIdx.x >> 6] = v;
    __syncthreads();
    if (threadIdx.x == 0) {
        float s = 0.f;
#pragma unroll
        for (int i = 0; i < 16; ++i) s += r[i];
        out[QSIZE + NTOK] = s;
    }
}
} // namespace

extern "C" void kernel_launch(void* const* d_in, const int* in_sizes, int n_in,
                              void* d_out, int out_size, void* d_ws, size_t ws_size,
                              hipStream_t stream) {
    const float* x  = (const float*)d_in[0];
    const float* cb = (const float*)d_in[1];
    float* out = (float*)d_out;
    float* partials = (float*)d_ws;   // 4096 floats; written before read each launch

    vq_main<<<NWAVE / 4, 256, 0, stream>>>(x, cb, out, partials);
    reduce_loss<<<1, 1024, 0, stream>>>(partials, out);
}